// Round 5
// baseline (189.042 us; speedup 1.0000x reference)
//
#include <hip/hip_runtime.h>
#include <math.h>

typedef __bf16 bf16x8 __attribute__((ext_vector_type(8)));
typedef __bf16 bf16x4 __attribute__((ext_vector_type(4)));
typedef float f32x4 __attribute__((ext_vector_type(4)));

#define B_SZ 512
#define IN_F 342
#define HID  512
#define OUT_F 311
#define K0P  1536   // 4*IN_F = 1368 padded to multiple of 256
#define K12  2048   // 4*HID
#define N2P  320    // OUT_F padded
#define NFLAGS (64 + 64 + 40)

// ---------------------------------------------------------------------------
// prep: coef[b][4] + layer-0 expanded bf16 input A0 (zero tail to K0P).
// Block 0 additionally zeroes the split-K flags (re-armed every call).
// ---------------------------------------------------------------------------
__global__ __launch_bounds__(256) void prep_kernel(const float* __restrict__ p,
                                                   const float* __restrict__ x,
                                                   float* __restrict__ coef,
                                                   __bf16* __restrict__ A0,
                                                   int* __restrict__ flags) {
  int b = blockIdx.x;
  int tid = threadIdx.x;
  if (b == 0 && tid < NFLAGS) flags[tid] = 0;
  __shared__ float cf[4];
  if (tid == 0) {
    float p4 = p[b] * 4.0f;
    float mu = p4 - floorf(p4);
    int i1 = ((int)p4) & 3;
    float mu2 = mu * mu, mu3 = mu2 * mu;
    float c0 = -0.5f * mu3 + mu2 - 0.5f * mu;
    float c1 =  1.5f * mu3 - 2.5f * mu2 + 1.0f;
    float c2 = -1.5f * mu3 + 2.0f * mu2 + 0.5f * mu;
    float c3 =  0.5f * mu3 - 0.5f * mu2;
    cf[(i1 + 3) & 3] = c0;
    cf[i1]           = c1;
    cf[(i1 + 1) & 3] = c2;
    cf[(i1 + 2) & 3] = c3;
  }
  __syncthreads();
  if (tid < 4) coef[b * 4 + tid] = cf[tid];
  float c0 = cf[0], c1 = cf[1], c2 = cf[2], c3 = cf[3];
  const float* xr = x + (size_t)b * IN_F;
  __bf16* dst = A0 + (size_t)b * K0P;
  for (int i = tid; i < IN_F; i += 256) {
    float xv = xr[i];
    dst[i]            = (__bf16)(c0 * xv);
    dst[IN_F + i]     = (__bf16)(c1 * xv);
    dst[2 * IN_F + i] = (__bf16)(c2 * xv);
    dst[3 * IN_F + i] = (__bf16)(c3 * xv);
  }
  for (int k = 4 * IN_F + tid; k < K0P; k += 256) dst[k] = (__bf16)0.0f;
}

// ---------------------------------------------------------------------------
// Fused split-K bf16 MFMA GEMM + last-block epilogue.
//  A  : M x Ka bf16 (padded, zero tail)
//  W  : kLog x nLog fp32 (original layout) — transposed+converted during
//       staging into LDS [n][k]
//  Block (nx,my,z): 64x64 tile, K range [z*C,(z+1)*C), T=C/64 even.
//  Partials -> P[z][512][Np] fp32; last sibling (atomic flag) reduces in
//  FIXED slice order + bias-interp (+ ELU + 4-copy expand if EXPAND).
// ---------------------------------------------------------------------------
template <int EXPAND, int SPLIT, int VEC>
__global__ __launch_bounds__(256) void gemm_fused(
    const __bf16* __restrict__ A, const float* __restrict__ W,
    const float* __restrict__ bias, const float* __restrict__ coef,
    void* __restrict__ outv, float* __restrict__ P, int* __restrict__ flags,
    int Ka, int kLog, int Np, int nLog, int C) {
  constexpr int LDT = 72;
  __shared__ __bf16 Als[64 * LDT];
  __shared__ __bf16 Bls[64 * LDT];

  const int tid = threadIdx.x;
  const int l = tid & 63;
  const int wave = tid >> 6;
  const int wm = wave >> 1, wn = wave & 1;
  const int lr = l & 15, lk = l >> 4;
  const int m0 = blockIdx.y * 64;
  const int n0 = blockIdx.x * 64;
  const int kbase = blockIdx.z * C;
  const int T = C >> 6;

  // A staging: row ar (0..63), two octets starting at ao
  const int ar = tid >> 2;
  const int ao = (tid & 3) * 2;
  const __bf16* Ap = A + (size_t)(m0 + ar) * Ka + kbase + ao * 8;

  // B staging: 4x4 block at rows kb*4.., cols nb*4..
  const int kb = tid >> 4;
  const int nb = tid & 15;
  const float* Wp = W + (size_t)(kbase + kb * 4) * nLog + n0 + nb * 4;

  bf16x8 a0_, a1_, a2_, a3_;               // A double buffer (2 per phase)
  f32x4 p0r0, p0r1, p0r2, p0r3;            // B phase 0 (4 rows)
  f32x4 p1r0, p1r1, p1r2, p1r3;            // B phase 1
  f32x4 acc[2][2] = {};

  auto loadB = [&](int t, f32x4& r0, f32x4& r1, f32x4& r2, f32x4& r3) {
    const float* wp = Wp + (size_t)t * 64 * nLog;
    int k0 = kbase + t * 64 + kb * 4;
    if (VEC) {
      r0 = (k0 + 0 < kLog) ? *(const f32x4*)(wp)            : f32x4{};
      r1 = (k0 + 1 < kLog) ? *(const f32x4*)(wp + nLog)     : f32x4{};
      r2 = (k0 + 2 < kLog) ? *(const f32x4*)(wp + 2 * nLog) : f32x4{};
      r3 = (k0 + 3 < kLog) ? *(const f32x4*)(wp + 3 * nLog) : f32x4{};
    } else {
      int n = n0 + nb * 4;
      f32x4 rr[1];
#pragma unroll
      for (int r = 0; r < 4; ++r) {
        f32x4 v{};
#pragma unroll
        for (int j = 0; j < 4; ++j)
          v[j] = (k0 + r < kLog && n + j < nLog) ? wp[(size_t)r * nLog + j] : 0.0f;
        if (r == 0) r0 = v; else if (r == 1) r1 = v; else if (r == 2) r2 = v; else r3 = v;
      }
      (void)rr;
    }
  };
  auto load0 = [&](int t) {
    a0_ = *(const bf16x8*)&Ap[t * 64];
    a1_ = *(const bf16x8*)&Ap[t * 64 + 8];
    loadB(t, p0r0, p0r1, p0r2, p0r3);
  };
  auto load1 = [&](int t) {
    a2_ = *(const bf16x8*)&Ap[t * 64];
    a3_ = *(const bf16x8*)&Ap[t * 64 + 8];
    loadB(t, p1r0, p1r1, p1r2, p1r3);
  };
  auto storeB = [&](const f32x4& r0, const f32x4& r1, const f32x4& r2,
                    const f32x4& r3) {
#pragma unroll
    for (int j = 0; j < 4; ++j) {
      bf16x4 v = {(__bf16)r0[j], (__bf16)r1[j], (__bf16)r2[j], (__bf16)r3[j]};
      *(bf16x4*)&Bls[(nb * 4 + j) * LDT + kb * 4] = v;
    }
  };
  auto store0 = [&]() {
    *(bf16x8*)&Als[ar * LDT + ao * 8] = a0_;
    *(bf16x8*)&Als[ar * LDT + ao * 8 + 8] = a1_;
    storeB(p0r0, p0r1, p0r2, p0r3);
  };
  auto store1 = [&]() {
    *(bf16x8*)&Als[ar * LDT + ao * 8] = a2_;
    *(bf16x8*)&Als[ar * LDT + ao * 8 + 8] = a3_;
    storeB(p1r0, p1r1, p1r2, p1r3);
  };
  auto compute = [&]() {
#pragma unroll
    for (int kk = 0; kk < 64; kk += 32) {
      bf16x8 af[2], bg[2];
#pragma unroll
      for (int i = 0; i < 2; ++i) {
        af[i] = *(const bf16x8*)&Als[(wm * 32 + i * 16 + lr) * LDT + kk + lk * 8];
        bg[i] = *(const bf16x8*)&Bls[(wn * 32 + i * 16 + lr) * LDT + kk + lk * 8];
      }
#pragma unroll
      for (int i = 0; i < 2; ++i)
#pragma unroll
        for (int j = 0; j < 2; ++j)
          acc[i][j] = __builtin_amdgcn_mfma_f32_16x16x32_bf16(af[i], bg[j],
                                                              acc[i][j], 0, 0, 0);
    }
  };

  load0(0);
  load1(1);
  for (int t = 0; t < T; t += 2) {
    __syncthreads();
    store0();
    __syncthreads();
    if (t + 2 < T) load0(t + 2);
    compute();
    __syncthreads();
    store1();
    __syncthreads();
    if (t + 3 < T) load1(t + 3);
    compute();
  }

  // write partials
  float* Pp = P + (size_t)blockIdx.z * B_SZ * Np;
#pragma unroll
  for (int i = 0; i < 2; ++i)
#pragma unroll
    for (int j = 0; j < 2; ++j) {
      int gn = n0 + wn * 32 + j * 16 + lr;
#pragma unroll
      for (int r = 0; r < 4; ++r) {
        int gm = m0 + wm * 32 + i * 16 + lk * 4 + r;
        Pp[(size_t)gm * Np + gn] = acc[i][j][r];
      }
    }

  // ---- split-K election: last sibling does the epilogue ----
  __shared__ int elect;
  __threadfence();          // release our P stores (device scope)
  __syncthreads();
  if (tid == 0) {
    int tile = blockIdx.y * gridDim.x + blockIdx.x;
    int old = atomicAdd(&flags[tile], 1);
    elect = (old == SPLIT - 1);
  }
  __syncthreads();
  if (!elect) return;
  __threadfence();          // acquire: see siblings' P stores

  const int ml = tid >> 2;
  const int nseg = (tid & 3) * 16;
  const int gm = m0 + ml;
  f32x4 cf = *(const f32x4*)&coef[gm * 4];

#pragma unroll
  for (int c4 = 0; c4 < 4; ++c4) {
    int gnb = n0 + nseg + c4 * 4;
    f32x4 s{};
#pragma unroll
    for (int z2 = 0; z2 < SPLIT; ++z2)   // FIXED order -> deterministic
      s += *(const f32x4*)&P[(size_t)(z2 * B_SZ + gm) * Np + gnb];
    if (EXPAND) {
      // bias rows stride nLog (=512), aligned
      f32x4 b0v = *(const f32x4*)&bias[gnb];
      f32x4 b1v = *(const f32x4*)&bias[nLog + gnb];
      f32x4 b2v = *(const f32x4*)&bias[2 * nLog + gnb];
      f32x4 b3v = *(const f32x4*)&bias[3 * nLog + gnb];
      f32x4 v = s + cf[0] * b0v + cf[1] * b1v + cf[2] * b2v + cf[3] * b3v;
      __bf16* an = (__bf16*)outv + (size_t)gm * (4 * nLog) + gnb;
#pragma unroll
      for (int c = 0; c < 4; ++c) {
        bf16x4 o;
#pragma unroll
        for (int j = 0; j < 4; ++j) {
          float e = v[j];
          e = (e > 0.0f) ? e : expm1f(e);
          o[j] = (__bf16)(cf[c] * e);
        }
        *(bf16x4*)&an[(size_t)c * nLog] = o;
      }
    } else {
      float* op = (float*)outv;
#pragma unroll
      for (int j = 0; j < 4; ++j) {
        int gn = gnb + j;
        if (gn < nLog) {
          float bi = cf[0] * bias[gn] + cf[1] * bias[nLog + gn] +
                     cf[2] * bias[2 * nLog + gn] + cf[3] * bias[3 * nLog + gn];
          op[(size_t)gm * nLog + gn] = s[j] + bi;
        }
      }
    }
  }
}

extern "C" void kernel_launch(void* const* d_in, const int* in_sizes, int n_in,
                              void* d_out, int out_size, void* d_ws, size_t ws_size,
                              hipStream_t stream) {
  const float* p  = (const float*)d_in[0];
  const float* x  = (const float*)d_in[1];
  const float* W0 = (const float*)d_in[2];
  const float* b0 = (const float*)d_in[3];
  const float* W1 = (const float*)d_in[4];
  const float* b1 = (const float*)d_in[5];
  const float* W2 = (const float*)d_in[6];
  const float* b2 = (const float*)d_in[7];
  float* out = (float*)d_out;

  char* w = (char*)d_ws;
  float*  coef = (float*)w;      w += 8192;
  __bf16* A0   = (__bf16*)w;     w += (size_t)B_SZ * K0P * 2;
  __bf16* A1   = (__bf16*)w;     w += (size_t)B_SZ * K12 * 2;
  __bf16* A2   = (__bf16*)w;     w += (size_t)B_SZ * K12 * 2;
  float*  P    = (float*)w;      w += (size_t)8 * B_SZ * HID * 4;  // 8 MB max
  int*  flags  = (int*)w;        // NFLAGS ints: [0,64) L0, [64,128) L1, [128,168) L2
  int* f0 = flags, *f1 = flags + 64, *f2 = flags + 128;

  prep_kernel<<<B_SZ, 256, 0, stream>>>(p, x, coef, A0, flags);

  // L0: A0(512x1536) @ W0(1368x512) -> ELU+expand -> A1 (bf16 512x2048)
  gemm_fused<1, 4, 1><<<dim3(8, 8, 4), 256, 0, stream>>>(
      A0, W0, b0, coef, A1, P, f0, K0P, 4 * IN_F, HID, HID, K0P / 4);
  // L1: A1(512x2048) @ W1(2048x512) -> ELU+expand -> A2 (bf16 512x2048)
  gemm_fused<1, 8, 1><<<dim3(8, 8, 8), 256, 0, stream>>>(
      A1, W1, b1, coef, A2, P, f1, K12, K12, HID, HID, K12 / 8);
  // L2: A2(512x2048) @ W2(2048x311) -> out (fp32 512x311)
  gemm_fused<0, 8, 0><<<dim3(N2P / 64, 8, 8), 256, 0, stream>>>(
      A2, W2, b2, coef, out, P, f2, K12, K12, N2P, OUT_F, K12 / 8);
}

// Round 6
// 135.414 us; speedup vs baseline: 1.3960x; 1.3960x over previous
//
#include <hip/hip_runtime.h>
#include <math.h>

typedef __bf16 bf16x8 __attribute__((ext_vector_type(8)));
typedef __bf16 bf16x4 __attribute__((ext_vector_type(4)));
typedef float f32x4 __attribute__((ext_vector_type(4)));

#define B_SZ 512
#define IN_F 342
#define HID  512
#define OUT_F 311
#define K0P  1536   // 4*IN_F = 1368 padded to multiple of 256
#define K12  2048   // 4*HID
#define N2P  320    // OUT_F padded
#define SPLIT 4
#define NFLAGS (64 + 64 + 40)

// ---------------------------------------------------------------------------
// setup (one launch, 1120 blocks):
//  blocks 0..511    : prep — coef[b][4] + layer-0 expanded bf16 input A0
//                     (block 0 also zeroes the split-K election flags)
//  blocks 512..1119 : weight transpose+convert W(KxN f32) -> WT(Np x Kp bf16)
// ---------------------------------------------------------------------------
__global__ __launch_bounds__(256) void setup_kernel(
    const float* __restrict__ p, const float* __restrict__ x,
    const float* __restrict__ W0, const float* __restrict__ W1,
    const float* __restrict__ W2, float* __restrict__ coef,
    __bf16* __restrict__ A0, __bf16* __restrict__ T0,
    __bf16* __restrict__ T1, __bf16* __restrict__ T2,
    int* __restrict__ flags) {
  int bid = blockIdx.x;
  int tid = threadIdx.x;
  if (bid < B_SZ) {
    // ---- prep path ----
    if (bid == 0 && tid < NFLAGS) flags[tid] = 0;
    int b = bid;
    __shared__ float cf[4];
    if (tid == 0) {
      float p4 = p[b] * 4.0f;
      float mu = p4 - floorf(p4);
      int i1 = ((int)p4) & 3;
      float mu2 = mu * mu, mu3 = mu2 * mu;
      float c0 = -0.5f * mu3 + mu2 - 0.5f * mu;
      float c1 =  1.5f * mu3 - 2.5f * mu2 + 1.0f;
      float c2 = -1.5f * mu3 + 2.0f * mu2 + 0.5f * mu;
      float c3 =  0.5f * mu3 - 0.5f * mu2;
      cf[(i1 + 3) & 3] = c0;
      cf[i1]           = c1;
      cf[(i1 + 1) & 3] = c2;
      cf[(i1 + 2) & 3] = c3;
    }
    __syncthreads();
    if (tid < 4) coef[b * 4 + tid] = cf[tid];
    float c0 = cf[0], c1 = cf[1], c2 = cf[2], c3 = cf[3];
    const float* xr = x + (size_t)b * IN_F;
    __bf16* dst = A0 + (size_t)b * K0P;
    for (int i = tid; i < IN_F; i += 256) {
      float xv = xr[i];
      dst[i]            = (__bf16)(c0 * xv);
      dst[IN_F + i]     = (__bf16)(c1 * xv);
      dst[2 * IN_F + i] = (__bf16)(c2 * xv);
      dst[3 * IN_F + i] = (__bf16)(c3 * xv);
    }
    for (int k = 4 * IN_F + tid; k < K0P; k += 256) dst[k] = (__bf16)0.0f;
    return;
  }
  // ---- transpose path ----
  bid -= B_SZ;
  const float* W; __bf16* T; int K, N, Kp, tk, t;
  if (bid < 192)      { W = W0; T = T0; K = 1368; N = 512; Kp = K0P; t = bid;       tk = 24; }
  else if (bid < 448) { W = W1; T = T1; K = 2048; N = 512; Kp = K12; t = bid - 192; tk = 32; }
  else                { W = W2; T = T2; K = 2048; N = 311; Kp = K12; t = bid - 448; tk = 32; }
  int k0 = (t % tk) * 64, n0 = (t / tk) * 64;
  __shared__ __bf16 tile[64][66];  // 66: conflict-free b16 transposed writes
  int nl = tid & 63, n = n0 + nl;
#pragma unroll
  for (int r = 0; r < 16; ++r) {
    int kl = (tid >> 6) + r * 4;
    int k = k0 + kl;
    float v = (k < K && n < N) ? W[(size_t)k * N + n] : 0.0f;
    tile[nl][kl] = (__bf16)v;
  }
  __syncthreads();
  int row = tid >> 2, o0 = (tid & 3) * 2;
  bf16x8 v0 = *(const bf16x8*)&tile[row][o0 * 8];
  bf16x8 v1 = *(const bf16x8*)&tile[row][o0 * 8 + 8];
  __bf16* dst = T + (size_t)(n0 + row) * Kp + k0 + o0 * 8;
  *(bf16x8*)dst = v0;
  *(bf16x8*)(dst + 8) = v1;
}

// ---------------------------------------------------------------------------
// Fused split-K bf16 MFMA GEMM + last-block epilogue.
//  A: M x Ka bf16, BT: Np x Ka bf16 (k-major), both padded -> no bounds checks
//  Block (nx,my,z): 64x64 tile, K range [z*C,(z+1)*C), T=C/64 even.
//  2-deep reg prefetch, statically-named phase buffers (rule #20).
//  Partials -> P[z][512][Np]; last sibling per tile (atomic flag) reduces in
//  FIXED slice order (deterministic) + bias-interp (+ ELU + expand).
// ---------------------------------------------------------------------------
template <int EXPAND>
__global__ __launch_bounds__(256) void gemm_fused(
    const __bf16* __restrict__ A, const __bf16* __restrict__ BT,
    const float* __restrict__ bias, const float* __restrict__ coef,
    void* __restrict__ outv, float* __restrict__ P, int* __restrict__ flags,
    int Ka, int Np, int nLog, int C) {
  constexpr int LDT = 72;
  __shared__ __bf16 Als[64 * LDT];
  __shared__ __bf16 Bls[64 * LDT];

  const int tid = threadIdx.x;
  const int l = tid & 63;
  const int wave = tid >> 6;
  const int wm = wave >> 1, wn = wave & 1;
  const int lr = l & 15, lk = l >> 4;
  const int m0 = blockIdx.y * 64;
  const int n0 = blockIdx.x * 64;
  const int kbase = blockIdx.z * C;
  const int T = C >> 6;

  const int ar = tid >> 2;        // staging row 0..63
  const int ao = (tid & 3) * 2;   // first octet within 64-wide window

  const __bf16* Ap = A + (size_t)(m0 + ar) * Ka + kbase + ao * 8;
  const __bf16* Bp = BT + (size_t)(n0 + ar) * Ka + kbase + ao * 8;

  bf16x8 a0_, a1_, b0_, b1_;   // phase 0
  bf16x8 a2_, a3_, b2_, b3_;   // phase 1
  f32x4 acc[2][2] = {};

  auto load0 = [&](int t) {
    a0_ = *(const bf16x8*)&Ap[t * 64];
    a1_ = *(const bf16x8*)&Ap[t * 64 + 8];
    b0_ = *(const bf16x8*)&Bp[t * 64];
    b1_ = *(const bf16x8*)&Bp[t * 64 + 8];
  };
  auto load1 = [&](int t) {
    a2_ = *(const bf16x8*)&Ap[t * 64];
    a3_ = *(const bf16x8*)&Ap[t * 64 + 8];
    b2_ = *(const bf16x8*)&Bp[t * 64];
    b3_ = *(const bf16x8*)&Bp[t * 64 + 8];
  };
  auto store0 = [&]() {
    *(bf16x8*)&Als[ar * LDT + ao * 8] = a0_;
    *(bf16x8*)&Als[ar * LDT + ao * 8 + 8] = a1_;
    *(bf16x8*)&Bls[ar * LDT + ao * 8] = b0_;
    *(bf16x8*)&Bls[ar * LDT + ao * 8 + 8] = b1_;
  };
  auto store1 = [&]() {
    *(bf16x8*)&Als[ar * LDT + ao * 8] = a2_;
    *(bf16x8*)&Als[ar * LDT + ao * 8 + 8] = a3_;
    *(bf16x8*)&Bls[ar * LDT + ao * 8] = b2_;
    *(bf16x8*)&Bls[ar * LDT + ao * 8 + 8] = b3_;
  };
  auto compute = [&]() {
#pragma unroll
    for (int kk = 0; kk < 64; kk += 32) {
      bf16x8 af[2], bg[2];
#pragma unroll
      for (int i = 0; i < 2; ++i) {
        af[i] = *(const bf16x8*)&Als[(wm * 32 + i * 16 + lr) * LDT + kk + lk * 8];
        bg[i] = *(const bf16x8*)&Bls[(wn * 32 + i * 16 + lr) * LDT + kk + lk * 8];
      }
#pragma unroll
      for (int i = 0; i < 2; ++i)
#pragma unroll
        for (int j = 0; j < 2; ++j)
          acc[i][j] = __builtin_amdgcn_mfma_f32_16x16x32_bf16(af[i], bg[j],
                                                              acc[i][j], 0, 0, 0);
    }
  };

  load0(0);
  load1(1);
  for (int t = 0; t < T; t += 2) {
    __syncthreads();
    store0();
    __syncthreads();
    if (t + 2 < T) load0(t + 2);
    compute();
    __syncthreads();
    store1();
    __syncthreads();
    if (t + 3 < T) load1(t + 3);
    compute();
  }

  // write partials
  float* Pp = P + (size_t)blockIdx.z * B_SZ * Np;
#pragma unroll
  for (int i = 0; i < 2; ++i)
#pragma unroll
    for (int j = 0; j < 2; ++j) {
      int gn = n0 + wn * 32 + j * 16 + lr;
#pragma unroll
      for (int r = 0; r < 4; ++r) {
        int gm = m0 + wm * 32 + i * 16 + lk * 4 + r;
        Pp[(size_t)gm * Np + gn] = acc[i][j][r];
      }
    }

  // ---- split-K election: last sibling per tile does the epilogue ----
  __shared__ int elect;
  __threadfence();          // release our P stores (device scope)
  __syncthreads();
  if (tid == 0) {
    int tile = blockIdx.y * gridDim.x + blockIdx.x;
    int old = atomicAdd(&flags[tile], 1);
    elect = (old == SPLIT - 1);
  }
  __syncthreads();
  if (!elect) return;
  __threadfence();          // acquire: see siblings' P stores

  const int ml = tid >> 2;
  const int nseg = (tid & 3) * 16;
  const int gm = m0 + ml;
  f32x4 cf = *(const f32x4*)&coef[gm * 4];

#pragma unroll
  for (int c4 = 0; c4 < 4; ++c4) {
    int gnb = n0 + nseg + c4 * 4;
    f32x4 s{};
#pragma unroll
    for (int z2 = 0; z2 < SPLIT; ++z2)   // FIXED order -> deterministic
      s += *(const f32x4*)&P[(size_t)(z2 * B_SZ + gm) * Np + gnb];
    if (EXPAND) {
      f32x4 b0v = *(const f32x4*)&bias[gnb];
      f32x4 b1v = *(const f32x4*)&bias[nLog + gnb];
      f32x4 b2v = *(const f32x4*)&bias[2 * nLog + gnb];
      f32x4 b3v = *(const f32x4*)&bias[3 * nLog + gnb];
      f32x4 v = s + cf[0] * b0v + cf[1] * b1v + cf[2] * b2v + cf[3] * b3v;
      __bf16* an = (__bf16*)outv + (size_t)gm * (4 * nLog) + gnb;
#pragma unroll
      for (int c = 0; c < 4; ++c) {
        bf16x4 o;
#pragma unroll
        for (int j = 0; j < 4; ++j) {
          float e = v[j];
          e = (e > 0.0f) ? e : expm1f(e);
          o[j] = (__bf16)(cf[c] * e);
        }
        *(bf16x4*)&an[(size_t)c * nLog] = o;
      }
    } else {
      float* op = (float*)outv;
#pragma unroll
      for (int j = 0; j < 4; ++j) {
        int gn = gnb + j;
        if (gn < nLog) {
          float bi = cf[0] * bias[gn] + cf[1] * bias[nLog + gn] +
                     cf[2] * bias[2 * nLog + gn] + cf[3] * bias[3 * nLog + gn];
          op[(size_t)gm * nLog + gn] = s[j] + bi;
        }
      }
    }
  }
}

extern "C" void kernel_launch(void* const* d_in, const int* in_sizes, int n_in,
                              void* d_out, int out_size, void* d_ws, size_t ws_size,
                              hipStream_t stream) {
  const float* p  = (const float*)d_in[0];
  const float* x  = (const float*)d_in[1];
  const float* W0 = (const float*)d_in[2];
  const float* b0 = (const float*)d_in[3];
  const float* W1 = (const float*)d_in[4];
  const float* b1 = (const float*)d_in[5];
  const float* W2 = (const float*)d_in[6];
  const float* b2 = (const float*)d_in[7];
  float* out = (float*)d_out;

  char* w = (char*)d_ws;
  float*  coef = (float*)w;      w += 8192;
  __bf16* A0   = (__bf16*)w;     w += (size_t)B_SZ * K0P * 2;
  __bf16* A1   = (__bf16*)w;     w += (size_t)B_SZ * K12 * 2;
  __bf16* A2   = (__bf16*)w;     w += (size_t)B_SZ * K12 * 2;
  __bf16* WT0  = (__bf16*)w;     w += (size_t)HID * K0P * 2;
  __bf16* WT1  = (__bf16*)w;     w += (size_t)HID * K12 * 2;
  __bf16* WT2  = (__bf16*)w;     w += (size_t)N2P * K12 * 2;
  float*  P    = (float*)w;      w += (size_t)SPLIT * B_SZ * HID * 4;  // 4 MB
  int*  flags  = (int*)w;        // NFLAGS ints
  int* f0 = flags, *f1 = flags + 64, *f2 = flags + 128;

  setup_kernel<<<B_SZ + 608, 256, 0, stream>>>(p, x, W0, W1, W2, coef, A0,
                                               WT0, WT1, WT2, flags);

  // L0: A0(512x1536) @ WT0^T -> ELU+expand -> A1 (bf16 512x2048)
  gemm_fused<1><<<dim3(8, 8, SPLIT), 256, 0, stream>>>(
      A0, WT0, b0, coef, A1, P, f0, K0P, HID, HID, K0P / SPLIT);
  // L1: A1(512x2048) @ WT1^T -> ELU+expand -> A2 (bf16 512x2048)
  gemm_fused<1><<<dim3(8, 8, SPLIT), 256, 0, stream>>>(
      A1, WT1, b1, coef, A2, P, f1, K12, HID, HID, K12 / SPLIT);
  // L2: A2(512x2048) @ WT2^T -> out (fp32 512x311)
  gemm_fused<0><<<dim3(N2P / 64, 8, SPLIT), 256, 0, stream>>>(
      A2, WT2, b2, coef, out, P, f2, K12, N2P, OUT_F, K12 / SPLIT);
}

// Round 7
// 88.973 us; speedup vs baseline: 2.1247x; 1.5220x over previous
//
#include <hip/hip_runtime.h>
#include <math.h>

typedef __bf16 bf16x8 __attribute__((ext_vector_type(8)));
typedef __bf16 bf16x4 __attribute__((ext_vector_type(4)));
typedef float f32x4 __attribute__((ext_vector_type(4)));

#define B_SZ 512
#define IN_F 342
#define HID  512
#define OUT_F 311
#define N2P  320    // OUT_F padded to 64
#define K0P  1536   // 4 slices x 384 (IN_F padded to 384 per slice)
#define K12  2048   // 4 x HID

// ---------------------------------------------------------------------------
// setup: blocks 0..607 transpose+convert weights; block 608 computes coef.
//  WT0[n][k], k=c*384+i (zero for i>=342)   (512 x 1536 bf16)
//  WT1[n][k], k=c*512+h                     (512 x 2048 bf16)
//  WT2[n][k], rows n>=311 zero              (320 x 2048 bf16)
// ---------------------------------------------------------------------------
__global__ __launch_bounds__(256) void setup_kernel(
    const float* __restrict__ p, const float* __restrict__ W0,
    const float* __restrict__ W1, const float* __restrict__ W2,
    float* __restrict__ coef, __bf16* __restrict__ T0,
    __bf16* __restrict__ T1, __bf16* __restrict__ T2) {
  int bid = blockIdx.x, tid = threadIdx.x;
  if (bid == 608) {
    for (int b = tid; b < B_SZ; b += 256) {
      float p4 = p[b] * 4.0f;
      float mu = p4 - floorf(p4);
      int i1 = ((int)p4) & 3;
      float mu2 = mu * mu, mu3 = mu2 * mu;
      float c0 = -0.5f * mu3 + mu2 - 0.5f * mu;
      float c1 =  1.5f * mu3 - 2.5f * mu2 + 1.0f;
      float c2 = -1.5f * mu3 + 2.0f * mu2 + 0.5f * mu;
      float c3 =  0.5f * mu3 - 0.5f * mu2;
      float arr[4];
      arr[(i1 + 3) & 3] = c0;
      arr[i1]           = c1;
      arr[(i1 + 1) & 3] = c2;
      arr[(i1 + 2) & 3] = c3;
      coef[b * 4 + 0] = arr[0];
      coef[b * 4 + 1] = arr[1];
      coef[b * 4 + 2] = arr[2];
      coef[b * 4 + 3] = arr[3];
    }
    return;
  }
  const float* W; __bf16* T; int N, Kp, tk, t, job;
  if (bid < 192)      { W = W0; T = T0; N = 512; Kp = K0P; t = bid;       tk = 24; job = 0; }
  else if (bid < 448) { W = W1; T = T1; N = 512; Kp = K12; t = bid - 192; tk = 32; job = 1; }
  else                { W = W2; T = T2; N = 311; Kp = K12; t = bid - 448; tk = 32; job = 2; }
  int k0 = (t % tk) * 64, n0 = (t / tk) * 64;
  __shared__ __bf16 tile[64][66];
  int nl = tid & 63, n = n0 + nl;
#pragma unroll
  for (int r = 0; r < 16; ++r) {
    int kl = (tid >> 6) + r * 4;
    int k = k0 + kl;
    float v = 0.0f;
    if (job == 0) {
      int c = k / 384, i = k - c * 384;   // 384 % 64 == 0: c uniform per tile
      if (i < IN_F && n < N) v = W[(size_t)(c * IN_F + i) * 512 + n];
    } else {
      if (n < N) v = W[(size_t)k * ((job == 2) ? OUT_F : HID) + n];
    }
    tile[nl][kl] = (__bf16)v;
  }
  __syncthreads();
  int row = tid >> 2, o0 = (tid & 3) * 2;
  bf16x8 v0 = *(const bf16x8*)&tile[row][o0 * 8];
  bf16x8 v1 = *(const bf16x8*)&tile[row][o0 * 8 + 8];
  __bf16* dst = T + (size_t)(n0 + row) * Kp + k0 + o0 * 8;
  *(bf16x8*)dst = v0;
  *(bf16x8*)(dst + 8) = v1;
}

// ---------------------------------------------------------------------------
// gemm_layer<L>: block (nx,my,z) computes 64x64 output tile over K-range
// [z*C,(z+1)*C). PROLOGUE builds the block's OWN A-stripe in LDS from the
// previous layer's data (x for L0; P_prev reduced fixed-order + bias + ELU
// + cf-scale for L1/L2) — A never touches global, no fences needed
// (kernel boundary provides cross-XCD coherence). K-loop stages only B
// (bf16 WT, k-major) with statically-named 2-deep reg prefetch.
// Writes fp32 partials Pout[z][512][NP].
//  L0: C=768 (c-slices 2z,2z+1), grid (8,8,2), T=12
//  L1: C=512 (c-slice z),        grid (8,8,4), T=8,  reads P1 (2 slices)
//  L2: C=512 (c-slice z),        grid (5,8,4), T=8,  reads P2 (4 slices)
// ---------------------------------------------------------------------------
template <int LAYER>
__global__ __launch_bounds__(256) void gemm_layer(
    const float* __restrict__ src,       // L0: x; else P_prev
    const __bf16* __restrict__ WT,
    const float* __restrict__ biasPrev,  // L1: b0, L2: b1 (unused L0)
    const float* __restrict__ coef,
    float* __restrict__ Pout) {
  constexpr int C   = (LAYER == 0) ? 768 : 512;
  constexpr int T   = C / 64;
  constexpr int LDA = (LAYER == 0) ? 776 : 520;  // +8: rows land 4 banks apart
  constexpr int KA  = (LAYER == 0) ? K0P : K12;
  constexpr int NP  = (LAYER == 2) ? N2P : HID;
  constexpr int PS  = (LAYER == 1) ? 2 : 4;      // P_prev slice count
  constexpr int LDT = 72;
  __shared__ __bf16 Als[64 * LDA];
  __shared__ __bf16 Bls[64 * LDT];

  const int tid = threadIdx.x;
  const int l = tid & 63;
  const int wave = tid >> 6;
  const int wm = wave >> 1, wn = wave & 1;
  const int lr = l & 15, lk = l >> 4;
  const int m0 = blockIdx.y * 64;
  const int n0 = blockIdx.x * 64;
  const int zz = blockIdx.z;

  // B staging: row ar (n), two octets at ao (k)
  const int ar = tid >> 2;
  const int ao = (tid & 3) * 2;
  const __bf16* Bp = WT + (size_t)(n0 + ar) * KA + zz * C + ao * 8;

  bf16x8 b0_, b1_;   // phase 0
  bf16x8 b2_, b3_;   // phase 1
  f32x4 acc[2][2] = {};

  auto load0 = [&](int t) {
    b0_ = *(const bf16x8*)&Bp[t * 64];
    b1_ = *(const bf16x8*)&Bp[t * 64 + 8];
  };
  auto load1 = [&](int t) {
    b2_ = *(const bf16x8*)&Bp[t * 64];
    b3_ = *(const bf16x8*)&Bp[t * 64 + 8];
  };
  auto store0 = [&]() {
    *(bf16x8*)&Bls[ar * LDT + ao * 8] = b0_;
    *(bf16x8*)&Bls[ar * LDT + ao * 8 + 8] = b1_;
  };
  auto store1 = [&]() {
    *(bf16x8*)&Bls[ar * LDT + ao * 8] = b2_;
    *(bf16x8*)&Bls[ar * LDT + ao * 8 + 8] = b3_;
  };
  auto compute = [&](int t) {
#pragma unroll
    for (int kk = 0; kk < 64; kk += 32) {
      bf16x8 af[2], bg[2];
#pragma unroll
      for (int i = 0; i < 2; ++i) {
        af[i] = *(const bf16x8*)&Als[(wm * 32 + i * 16 + lr) * LDA + t * 64 + kk + lk * 8];
        bg[i] = *(const bf16x8*)&Bls[(wn * 32 + i * 16 + lr) * LDT + kk + lk * 8];
      }
#pragma unroll
      for (int i = 0; i < 2; ++i)
#pragma unroll
        for (int j = 0; j < 2; ++j)
          acc[i][j] = __builtin_amdgcn_mfma_f32_16x16x32_bf16(af[i], bg[j],
                                                              acc[i][j], 0, 0, 0);
    }
  };

  load0(0);   // B loads in flight while prologue computes
  load1(1);

  // ---- prologue: build A-stripe in LDS ----
  if (LAYER == 0) {
    // A[m][c*384+i] = cf[c]*x[m][i], c in {2z, 2z+1}
    const int lane = tid & 63, grp = tid >> 6;
    for (int r = grp; r < 64; r += 4) {
      const f32x4 cf = *(const f32x4*)&coef[(m0 + r) * 4];
      float s0 = zz ? cf[2] : cf[0];
      float s1 = zz ? cf[3] : cf[1];
      const float* xr = src + (size_t)(m0 + r) * IN_F;
#pragma unroll
      for (int j = 0; j < 6; ++j) {
        int i = lane + j * 64;
        if (i < IN_F) {
          float xv = xr[i];
          Als[r * LDA + i]       = (__bf16)(s0 * xv);
          Als[r * LDA + 384 + i] = (__bf16)(s1 * xv);
        }
      }
      if (lane < 384 - IN_F) {
        Als[r * LDA + IN_F + lane]       = (__bf16)0.0f;
        Als[r * LDA + 384 + IN_F + lane] = (__bf16)0.0f;
      }
    }
  } else {
    // A[m][n] = cf[z]*elu(sum_s P_prev[s][m][n] + bias_interp[m][n])
    const int half = tid >> 7;
    const int nn = (tid & 127) * 4;
    const f32x4 bb0 = *(const f32x4*)&biasPrev[nn];
    const f32x4 bb1 = *(const f32x4*)&biasPrev[HID + nn];
    const f32x4 bb2 = *(const f32x4*)&biasPrev[2 * HID + nn];
    const f32x4 bb3 = *(const f32x4*)&biasPrev[3 * HID + nn];
    for (int r2 = 0; r2 < 64; r2 += 2) {
      int r = r2 + half;
      int gm = m0 + r;
      f32x4 s = *(const f32x4*)&src[((size_t)0 * B_SZ + gm) * HID + nn];
      s += *(const f32x4*)&src[((size_t)1 * B_SZ + gm) * HID + nn];
      if (PS == 4) {
        s += *(const f32x4*)&src[((size_t)2 * B_SZ + gm) * HID + nn];
        s += *(const f32x4*)&src[((size_t)3 * B_SZ + gm) * HID + nn];
      }
      f32x4 cf = *(const f32x4*)&coef[gm * 4];
      f32x4 v = s + cf[0] * bb0 + cf[1] * bb1 + cf[2] * bb2 + cf[3] * bb3;
      float sc = (zz & 2) ? ((zz & 1) ? cf[3] : cf[2])
                          : ((zz & 1) ? cf[1] : cf[0]);
      bf16x4 o;
#pragma unroll
      for (int j = 0; j < 4; ++j) {
        float e = v[j];
        e = (e > 0.0f) ? e : expm1f(e);
        o[j] = (__bf16)(sc * e);
      }
      *(bf16x4*)&Als[r * LDA + nn] = o;
    }
  }

  // ---- K-loop (A resident in LDS; B double-buffered) ----
  for (int t = 0; t < T; t += 2) {
    __syncthreads();           // A_lds ready (t=0) / prev compute done
    store0();
    __syncthreads();
    if (t + 2 < T) load0(t + 2);
    compute(t);
    __syncthreads();
    store1();
    __syncthreads();
    if (t + 3 < T) load1(t + 3);
    compute(t + 1);
  }

  // ---- write partials ----
  float* Pp = Pout + (size_t)zz * B_SZ * NP;
#pragma unroll
  for (int i = 0; i < 2; ++i)
#pragma unroll
    for (int j = 0; j < 2; ++j) {
      int gn = n0 + wn * 32 + j * 16 + lr;
#pragma unroll
      for (int r = 0; r < 4; ++r) {
        int gm = m0 + wm * 32 + i * 16 + lk * 4 + r;
        Pp[(size_t)gm * NP + gn] = acc[i][j][r];
      }
    }
}

// ---------------------------------------------------------------------------
// final: out[m][n] = sum_s P3[s][m][n] + bias2_interp   (fp32, n < 311)
// ---------------------------------------------------------------------------
__global__ __launch_bounds__(256) void final_epi(
    const float* __restrict__ P3, const float* __restrict__ b2,
    const float* __restrict__ coef, float* __restrict__ out) {
  int m = blockIdx.x;
  f32x4 cf = *(const f32x4*)&coef[m * 4];
  for (int n = threadIdx.x; n < OUT_F; n += 256) {
    float s = P3[((size_t)0 * B_SZ + m) * N2P + n] +
              P3[((size_t)1 * B_SZ + m) * N2P + n] +
              P3[((size_t)2 * B_SZ + m) * N2P + n] +
              P3[((size_t)3 * B_SZ + m) * N2P + n];
    float bi = cf[0] * b2[n] + cf[1] * b2[OUT_F + n] +
               cf[2] * b2[2 * OUT_F + n] + cf[3] * b2[3 * OUT_F + n];
    out[(size_t)m * OUT_F + n] = s + bi;
  }
}

extern "C" void kernel_launch(void* const* d_in, const int* in_sizes, int n_in,
                              void* d_out, int out_size, void* d_ws, size_t ws_size,
                              hipStream_t stream) {
  const float* p  = (const float*)d_in[0];
  const float* x  = (const float*)d_in[1];
  const float* W0 = (const float*)d_in[2];
  const float* b0 = (const float*)d_in[3];
  const float* W1 = (const float*)d_in[4];
  const float* b1 = (const float*)d_in[5];
  const float* W2 = (const float*)d_in[6];
  const float* b2 = (const float*)d_in[7];
  float* out = (float*)d_out;

  char* w = (char*)d_ws;
  float*  coef = (float*)w;   w += 8192;
  __bf16* WT0  = (__bf16*)w;  w += (size_t)HID * K0P * 2;   // 1.5 MB
  __bf16* WT1  = (__bf16*)w;  w += (size_t)HID * K12 * 2;   // 2 MB
  __bf16* WT2  = (__bf16*)w;  w += (size_t)N2P * K12 * 2;   // 1.25 MB
  float*  P1   = (float*)w;   w += (size_t)2 * B_SZ * HID * 4;  // 2 MB
  float*  P2   = (float*)w;   w += (size_t)4 * B_SZ * HID * 4;  // 4 MB
  float*  P3   = (float*)w;   w += (size_t)4 * B_SZ * N2P * 4;  // 2.5 MB

  setup_kernel<<<609, 256, 0, stream>>>(p, W0, W1, W2, coef, WT0, WT1, WT2);

  gemm_layer<0><<<dim3(8, 8, 2), 256, 0, stream>>>(x,  WT0, nullptr, coef, P1);
  gemm_layer<1><<<dim3(8, 8, 4), 256, 0, stream>>>(P1, WT1, b0,      coef, P2);
  gemm_layer<2><<<dim3(5, 8, 4), 256, 0, stream>>>(P2, WT2, b1,      coef, P3);
  final_epi<<<B_SZ, 256, 0, stream>>>(P3, b2, coef, out);
}

// Round 8
// 56.728 us; speedup vs baseline: 3.3324x; 1.5684x over previous
//
#include <hip/hip_runtime.h>
#include <math.h>

typedef __bf16 bf16x8 __attribute__((ext_vector_type(8)));
typedef __bf16 bf16x4 __attribute__((ext_vector_type(4)));
typedef float f32x4 __attribute__((ext_vector_type(4)));

#define B_SZ 512
#define IN_F 342
#define HID  512
#define OUT_F 311
#define KA0  384    // IN_F padded
#define N2S  320    // per-slice padded width of layer-2 output
#define N2   1280   // 4*N2S

// ---------------------------------------------------------------------------
// setup (625 blocks):
//  0..191   WT0[c*512+h][i] = W0[c][i][h]   (2048 x 384 bf16, i>=342 -> 0)
//  192..447 WT1[c*512+h][k] = W1[c][k][h]   (2048 x 512 bf16)
//  448..607 WT2[c*320+n][k] = W2[c][k][n]   (1280 x 512 bf16, n>=311 -> 0)
//  608..623 A0[m][i] = bf16(x[m][i])        (512 x 384, i>=342 -> 0)
//  624      coef[b][4] (Catmull-Rom weights permuted by i1)
// ---------------------------------------------------------------------------
__global__ __launch_bounds__(256) void setup_kernel(
    const float* __restrict__ p, const float* __restrict__ x,
    const float* __restrict__ W0, const float* __restrict__ W1,
    const float* __restrict__ W2, float* __restrict__ coef,
    __bf16* __restrict__ A0, __bf16* __restrict__ T0,
    __bf16* __restrict__ T1, __bf16* __restrict__ T2) {
  int bid = blockIdx.x, tid = threadIdx.x;
  if (bid >= 608) {
    if (bid == 624) {
      for (int b = tid; b < B_SZ; b += 256) {
        float p4 = p[b] * 4.0f;
        float mu = p4 - floorf(p4);
        int i1 = ((int)p4) & 3;
        float mu2 = mu * mu, mu3 = mu2 * mu;
        float c0 = -0.5f * mu3 + mu2 - 0.5f * mu;
        float c1 =  1.5f * mu3 - 2.5f * mu2 + 1.0f;
        float c2 = -1.5f * mu3 + 2.0f * mu2 + 0.5f * mu;
        float c3 =  0.5f * mu3 - 0.5f * mu2;
        float arr[4];
        arr[(i1 + 3) & 3] = c0;
        arr[i1]           = c1;
        arr[(i1 + 1) & 3] = c2;
        arr[(i1 + 2) & 3] = c3;
        coef[b * 4 + 0] = arr[0];
        coef[b * 4 + 1] = arr[1];
        coef[b * 4 + 2] = arr[2];
        coef[b * 4 + 3] = arr[3];
      }
    } else {
      int base = (bid - 608) * 32;  // 32 rows of x per block
      for (int e = tid; e < 32 * KA0; e += 256) {
        int m = base + e / KA0, i = e % KA0;
        A0[(size_t)m * KA0 + i] =
            (i < IN_F) ? (__bf16)x[(size_t)m * IN_F + i] : (__bf16)0.0f;
      }
    }
    return;
  }
  // ---- weight transpose tiles (64x64) ----
  const float* W; __bf16* T; int t, job, Kp;
  if (bid < 192)      { job = 0; W = W0; T = T0; t = bid;       Kp = KA0; }
  else if (bid < 448) { job = 1; W = W1; T = T1; t = bid - 192; Kp = 512; }
  else                { job = 2; W = W2; T = T2; t = bid - 448; Kp = 512; }
  int R  = (job == 0) ? t / 6 : t / 8;
  int Kb = (job == 0) ? t % 6 : t % 8;
  int r0 = R * 64, k0 = Kb * 64;

  __shared__ __bf16 tile[64][66];
  int rl = tid & 63;
#pragma unroll
  for (int jj = 0; jj < 16; ++jj) {
    int kl = (tid >> 6) + jj * 4;
    int k = k0 + kl;
    float v = 0.0f;
    if (job == 0) {
      int c = r0 >> 9, h = (r0 & 511) + rl;
      if (k < IN_F) v = W[((size_t)c * IN_F + k) * 512 + h];
    } else if (job == 1) {
      int c = r0 >> 9, h = (r0 & 511) + rl;
      v = W[((size_t)c * HID + k) * 512 + h];
    } else {
      int c = r0 / N2S, n = r0 - c * N2S + rl;
      if (n < OUT_F) v = W[((size_t)c * HID + k) * OUT_F + n];
    }
    tile[rl][kl] = (__bf16)v;
  }
  __syncthreads();
  int row = tid >> 2, o0 = (tid & 3) * 16;
  bf16x8 v0 = *(const bf16x8*)&tile[row][o0];
  bf16x8 v1 = *(const bf16x8*)&tile[row][o0 + 8];
  __bf16* dst = T + (size_t)(r0 + row) * Kp + k0 + o0;
  *(bf16x8*)dst = v0;
  *(bf16x8*)(dst + 8) = v1;
}

// ---------------------------------------------------------------------------
// gemm_k<KA>: P[m][n] = A(M x KA bf16) @ BT(n x KA bf16, k-major), no scaling,
// no split-K. Block (nx,my): 64x64 tile. A-stripe staged ONCE, resident in
// LDS (row stride KA+8 -> 2-way banks, free). B double-buffered via
// statically-named regs (rule #20). T = KA/64 (6 or 8, even).
// ---------------------------------------------------------------------------
template <int KA>
__global__ __launch_bounds__(256) void gemm_k(const __bf16* __restrict__ A,
                                              const __bf16* __restrict__ BT,
                                              float* __restrict__ P, int Nst) {
  constexpr int T = KA / 64;
  constexpr int LDA = KA + 8;
  constexpr int LDT = 72;
  __shared__ __bf16 Als[64 * LDA];
  __shared__ __bf16 Bls[64 * LDT];

  const int tid = threadIdx.x;
  const int l = tid & 63;
  const int wave = tid >> 6;
  const int wm = wave >> 1, wn = wave & 1;
  const int lr = l & 15, lk = l >> 4;
  const int m0 = blockIdx.y * 64;
  const int n0 = blockIdx.x * 64;

  const int ar = tid >> 2;        // B staging row (n)
  const int ao = (tid & 3) * 2;   // first octet (k)
  const __bf16* Bp = BT + (size_t)(n0 + ar) * KA + ao * 8;

  bf16x8 b0_, b1_;   // phase 0
  bf16x8 b2_, b3_;   // phase 1
  f32x4 acc[2][2] = {};

  auto load0 = [&](int t) {
    b0_ = *(const bf16x8*)&Bp[t * 64];
    b1_ = *(const bf16x8*)&Bp[t * 64 + 8];
  };
  auto load1 = [&](int t) {
    b2_ = *(const bf16x8*)&Bp[t * 64];
    b3_ = *(const bf16x8*)&Bp[t * 64 + 8];
  };
  auto store0 = [&]() {
    *(bf16x8*)&Bls[ar * LDT + ao * 8] = b0_;
    *(bf16x8*)&Bls[ar * LDT + ao * 8 + 8] = b1_;
  };
  auto store1 = [&]() {
    *(bf16x8*)&Bls[ar * LDT + ao * 8] = b2_;
    *(bf16x8*)&Bls[ar * LDT + ao * 8 + 8] = b3_;
  };
  auto compute = [&](int t) {
#pragma unroll
    for (int kk = 0; kk < 64; kk += 32) {
      bf16x8 af[2], bg[2];
#pragma unroll
      for (int i = 0; i < 2; ++i) {
        af[i] = *(const bf16x8*)&Als[(wm * 32 + i * 16 + lr) * LDA + t * 64 + kk + lk * 8];
        bg[i] = *(const bf16x8*)&Bls[(wn * 32 + i * 16 + lr) * LDT + kk + lk * 8];
      }
#pragma unroll
      for (int i = 0; i < 2; ++i)
#pragma unroll
        for (int j = 0; j < 2; ++j)
          acc[i][j] = __builtin_amdgcn_mfma_f32_16x16x32_bf16(af[i], bg[j],
                                                              acc[i][j], 0, 0, 0);
    }
  };

  load0(0);   // B loads in flight while A-prologue runs
  load1(1);

  // ---- A-stripe -> LDS, once ----
  const int lane = tid & 63;
  for (int r = wave; r < 64; r += 4) {
    if (lane < KA / 8) {
      bf16x8 v = *(const bf16x8*)&A[(size_t)(m0 + r) * KA + lane * 8];
      *(bf16x8*)&Als[r * LDA + lane * 8] = v;
    }
  }

  for (int t = 0; t < T; t += 2) {
    __syncthreads();            // A ready (t=0) / prev compute done
    store0();
    __syncthreads();
    if (t + 2 < T) load0(t + 2);
    compute(t);
    __syncthreads();
    store1();
    __syncthreads();
    if (t + 3 < T) load1(t + 3);
    compute(t + 1);
  }

  // ---- write fp32 tile ----
#pragma unroll
  for (int i = 0; i < 2; ++i)
#pragma unroll
    for (int j = 0; j < 2; ++j) {
      int gn = n0 + wn * 32 + j * 16 + lr;
#pragma unroll
      for (int r = 0; r < 4; ++r) {
        int gm = m0 + wm * 32 + i * 16 + lk * 4 + r;
        P[(size_t)gm * Nst + gn] = acc[i][j][r];
      }
    }
}

// ---------------------------------------------------------------------------
// epi_mid: E[m][h] = bf16( elu( sum_c cf[m][c]*(P[m][c*512+h] + bias[c][h]) ))
// ---------------------------------------------------------------------------
__global__ __launch_bounds__(256) void epi_mid(const float* __restrict__ P,
                                               const float* __restrict__ bias,
                                               const float* __restrict__ coef,
                                               __bf16* __restrict__ E) {
  int idx = blockIdx.x * 256 + threadIdx.x;   // 65536 = 512*512/4
  int m = idx >> 7, h0 = (idx & 127) * 4;
  f32x4 cf = *(const f32x4*)&coef[m * 4];
  f32x4 v = {};
#pragma unroll
  for (int c = 0; c < 4; ++c) {
    f32x4 pv = *(const f32x4*)&P[(size_t)m * 2048 + c * 512 + h0];
    f32x4 bv = *(const f32x4*)&bias[c * 512 + h0];
    v += cf[c] * (pv + bv);
  }
  bf16x4 o;
#pragma unroll
  for (int j = 0; j < 4; ++j) {
    float e = v[j];
    e = (e > 0.0f) ? e : expm1f(e);
    o[j] = (__bf16)e;
  }
  *(bf16x4*)&E[(size_t)m * HID + h0] = o;
}

// ---------------------------------------------------------------------------
// epi_out: out[m][n] = sum_c cf[m][c]*(P3[m][c*320+n] + b2[c][n]),  n < 311
// ---------------------------------------------------------------------------
__global__ __launch_bounds__(256) void epi_out(const float* __restrict__ P3,
                                               const float* __restrict__ b2,
                                               const float* __restrict__ coef,
                                               float* __restrict__ out) {
  int m = blockIdx.x;
  f32x4 cf = *(const f32x4*)&coef[m * 4];
  for (int n = threadIdx.x; n < OUT_F; n += 256) {
    float v = 0.0f;
#pragma unroll
    for (int c = 0; c < 4; ++c)
      v += cf[c] * (P3[(size_t)m * N2 + c * N2S + n] + b2[c * OUT_F + n]);
    out[(size_t)m * OUT_F + n] = v;
  }
}

extern "C" void kernel_launch(void* const* d_in, const int* in_sizes, int n_in,
                              void* d_out, int out_size, void* d_ws, size_t ws_size,
                              hipStream_t stream) {
  const float* p  = (const float*)d_in[0];
  const float* x  = (const float*)d_in[1];
  const float* W0 = (const float*)d_in[2];
  const float* b0 = (const float*)d_in[3];
  const float* W1 = (const float*)d_in[4];
  const float* b1 = (const float*)d_in[5];
  const float* W2 = (const float*)d_in[6];
  const float* b2 = (const float*)d_in[7];
  float* out = (float*)d_out;

  char* w = (char*)d_ws;
  float*  coef = (float*)w;   w += 8192;
  __bf16* A0   = (__bf16*)w;  w += (size_t)B_SZ * KA0 * 2;    // 384 KB
  __bf16* T0   = (__bf16*)w;  w += (size_t)2048 * KA0 * 2;    // 1.5 MB
  __bf16* T1   = (__bf16*)w;  w += (size_t)2048 * 512 * 2;    // 2 MB
  __bf16* T2   = (__bf16*)w;  w += (size_t)N2 * 512 * 2;      // 1.25 MB
  __bf16* E1   = (__bf16*)w;  w += (size_t)B_SZ * HID * 2;    // 512 KB
  __bf16* E2   = (__bf16*)w;  w += (size_t)B_SZ * HID * 2;    // 512 KB
  float*  P1   = (float*)w;   w += (size_t)B_SZ * 2048 * 4;   // 4 MB
  float*  P2   = (float*)w;   w += (size_t)B_SZ * 2048 * 4;   // 4 MB
  float*  P3   = (float*)w;   w += (size_t)B_SZ * N2 * 4;     // 2.5 MB

  setup_kernel<<<625, 256, 0, stream>>>(p, x, W0, W1, W2, coef, A0, T0, T1, T2);

  gemm_k<KA0><<<dim3(32, 8), 256, 0, stream>>>(A0, T0, P1, 2048);
  epi_mid<<<256, 256, 0, stream>>>(P1, b0, coef, E1);

  gemm_k<512><<<dim3(32, 8), 256, 0, stream>>>(E1, T1, P2, 2048);
  epi_mid<<<256, 256, 0, stream>>>(P2, b1, coef, E2);

  gemm_k<512><<<dim3(20, 8), 256, 0, stream>>>(E2, T2, P3, N2);
  epi_out<<<B_SZ, 256, 0, stream>>>(P3, b2, coef, out);
}